// Round 11
// baseline (518.651 us; speedup 1.0000x reference)
//
#include <hip/hip_runtime.h>

#define D_IN  64
#define E_W   16
#define D_MSG 80
#define NXCD  8

static __device__ __forceinline__ void f4add(float4& a, const float4& b) {
    a.x += b.x; a.y += b.y; a.z += b.z; a.w += b.w;
}

// ---------------------------------------------------------------------------
// CSR build step 1: degree histogram, XCD-sharded (round-9, kept).
// ---------------------------------------------------------------------------
__global__ __launch_bounds__(256) void k_hist_sh(const int4* __restrict__ dst4,
                                                 const int* __restrict__ dst,
                                                 int* __restrict__ deg,
                                                 int E, int rng)
{
    int shard = blockIdx.x & (NXCD - 1);
    int wg    = blockIdx.x / NXCD;
    int lo    = shard * rng;
    int hi    = lo + rng;
    int E4    = E >> 2;

    int base = wg * 512;
    int stop = min(base + 512, E4);
    for (int i = base + threadIdx.x; i < stop; i += 256) {
        int4 d = dst4[i];
        if (d.x >= lo && d.x < hi) atomicAdd(deg + d.x, 1);
        if (d.y >= lo && d.y < hi) atomicAdd(deg + d.y, 1);
        if (d.z >= lo && d.z < hi) atomicAdd(deg + d.z, 1);
        if (d.w >= lo && d.w < hi) atomicAdd(deg + d.w, 1);
    }
    if (wg == 0 && threadIdx.x < (E & 3)) {
        int e = (E & ~3) + threadIdx.x;
        int d = dst[e];
        if (d >= lo && d < hi) atomicAdd(deg + d, 1);
    }
}

// ---------------------------------------------------------------------------
// CSR build step 2: 3-phase exclusive scan.
// ---------------------------------------------------------------------------
__global__ __launch_bounds__(256) void k_scan1(const int* __restrict__ deg,
                                               int* __restrict__ excl,
                                               int* __restrict__ bsums, int n)
{
    __shared__ int ts[256];
    int base = blockIdx.x * 1024 + threadIdx.x * 4;
    int v[4], s = 0;
    #pragma unroll
    for (int i = 0; i < 4; ++i) { v[i] = (base + i < n) ? deg[base + i] : 0; s += v[i]; }
    ts[threadIdx.x] = s; __syncthreads();
    #pragma unroll
    for (int off = 1; off < 256; off <<= 1) {
        int t = (threadIdx.x >= off) ? ts[threadIdx.x - off] : 0;
        __syncthreads();
        ts[threadIdx.x] += t;
        __syncthreads();
    }
    int run = ts[threadIdx.x] - s;
    if (threadIdx.x == 255) bsums[blockIdx.x] = ts[255];
    #pragma unroll
    for (int i = 0; i < 4; ++i) {
        if (base + i < n) excl[base + i] = run;
        run += v[i];
    }
}

__global__ __launch_bounds__(256) void k_scan2(int* __restrict__ bsums,
                                               int* __restrict__ bexcl, int nb)
{
    __shared__ int ts[256];
    int v = (threadIdx.x < nb) ? bsums[threadIdx.x] : 0;
    ts[threadIdx.x] = v; __syncthreads();
    #pragma unroll
    for (int off = 1; off < 256; off <<= 1) {
        int t = (threadIdx.x >= off) ? ts[threadIdx.x - off] : 0;
        __syncthreads();
        ts[threadIdx.x] += t;
        __syncthreads();
    }
    bexcl[threadIdx.x] = ts[threadIdx.x] - v;
}

__global__ __launch_bounds__(256) void k_scan3(const int* __restrict__ excl,
                                               const int* __restrict__ bexcl,
                                               int* __restrict__ offsets,
                                               int* __restrict__ cursor, int n, int E)
{
    int i = blockIdx.x * 256 + threadIdx.x;
    if (i < n) {
        int s = excl[i] + bexcl[i >> 10];
        offsets[i] = s;
        cursor[i]  = s;
    }
    if (i == 0) offsets[n] = E;
}

// ---------------------------------------------------------------------------
// CSR build step 3 (FULL tier): scatter src AND the 64B edge_w payload into
// dst-sorted order, XCD-sharded. edge_w is read SEQUENTIALLY here (e = 4i+c),
// killing pull's random 64B-in-128B-line gather (round-9: +102MB overfetch).
// Scattered 64B full-sector stores -> 1 sector writeback per edge.
// ---------------------------------------------------------------------------
__global__ __launch_bounds__(256) void k_reorder_ew(const int4* __restrict__ src4,
                                                    const int4* __restrict__ dst4,
                                                    const int* __restrict__ src,
                                                    const int* __restrict__ dst,
                                                    const float4* __restrict__ ew4,
                                                    int* __restrict__ cursor,
                                                    int* __restrict__ ssrc,
                                                    float4* __restrict__ sew4,
                                                    int E, int rng)
{
    int shard = blockIdx.x & (NXCD - 1);
    int wg    = blockIdx.x / NXCD;
    int lo    = shard * rng;
    int hi    = lo + rng;
    int E4    = E >> 2;

    int base = wg * 512;
    int stop = min(base + 512, E4);
    for (int i = base + threadIdx.x; i < stop; i += 256) {
        int4 d = dst4[i];
        bool h0 = (d.x >= lo && d.x < hi), h1 = (d.y >= lo && d.y < hi);
        bool h2 = (d.z >= lo && d.z < hi), h3 = (d.w >= lo && d.w < hi);
        if (!(h0 | h1 | h2 | h3)) continue;
        int4 s = src4[i];
        int e = i * 4;
        if (h0) {
            int pos = atomicAdd(cursor + d.x, 1); ssrc[pos] = s.x;
            const float4* sp = ew4 + (size_t)(e + 0) * 4;
            float4* dp = sew4 + (size_t)pos * 4;
            dp[0] = sp[0]; dp[1] = sp[1]; dp[2] = sp[2]; dp[3] = sp[3];
        }
        if (h1) {
            int pos = atomicAdd(cursor + d.y, 1); ssrc[pos] = s.y;
            const float4* sp = ew4 + (size_t)(e + 1) * 4;
            float4* dp = sew4 + (size_t)pos * 4;
            dp[0] = sp[0]; dp[1] = sp[1]; dp[2] = sp[2]; dp[3] = sp[3];
        }
        if (h2) {
            int pos = atomicAdd(cursor + d.z, 1); ssrc[pos] = s.z;
            const float4* sp = ew4 + (size_t)(e + 2) * 4;
            float4* dp = sew4 + (size_t)pos * 4;
            dp[0] = sp[0]; dp[1] = sp[1]; dp[2] = sp[2]; dp[3] = sp[3];
        }
        if (h3) {
            int pos = atomicAdd(cursor + d.w, 1); ssrc[pos] = s.w;
            const float4* sp = ew4 + (size_t)(e + 3) * 4;
            float4* dp = sew4 + (size_t)pos * 4;
            dp[0] = sp[0]; dp[1] = sp[1]; dp[2] = sp[2]; dp[3] = sp[3];
        }
    }
    if (wg == 0 && threadIdx.x < (E & 3)) {
        int e = (E & ~3) + threadIdx.x;
        int d = dst[e];
        if (d >= lo && d < hi) {
            int pos = atomicAdd(cursor + d, 1); ssrc[pos] = src[e];
            const float4* sp = ew4 + (size_t)e * 4;
            float4* dp = sew4 + (size_t)pos * 4;
            dp[0] = sp[0]; dp[1] = sp[1]; dp[2] = sp[2]; dp[3] = sp[3];
        }
    }
}

// ---------------------------------------------------------------------------
// FULL-tier pull: sequential sorted_ew stream, src-only index, no eid gather.
// ---------------------------------------------------------------------------
__global__ __launch_bounds__(256) void k_pull_seq(const float4* __restrict__ feat4,
                                                  const float4* __restrict__ sew4,
                                                  const int* __restrict__ ssrc,
                                                  const int* __restrict__ offsets,
                                                  float4* __restrict__ acc_h4,
                                                  float4* __restrict__ acc_w4, int N)
{
    int t = blockIdx.x * 256 + threadIdx.x;
    int node = t >> 4;
    if (node >= N) return;
    int l = t & 15;

    int beg = offsets[node];
    int end = offsets[node + 1];

    float4 ah = feat4[(size_t)node * 16 + l];   // eps-residual (EPS=0)
    float4 aw = make_float4(0.f, 0.f, 0.f, 0.f);

    if (beg < end) {
        int s0 = ssrc[beg];
        int s1 = (beg + 1 < end) ? ssrc[beg + 1] : 0;
        for (int p = beg; p < end; ++p) {
            int sn = (p + 2 < end) ? ssrc[p + 2] : 0;
            f4add(ah, feat4[(size_t)s0 * 16 + l]);
            if (l < 4) f4add(aw, sew4[(size_t)p * 4 + l]);   // sequential stream
            s0 = s1; s1 = sn;
        }
    }

    acc_h4[(size_t)node * 16 + l] = ah;
    if (l < 4) acc_w4[(size_t)node * 4 + l] = aw;
}

// ---------------------------------------------------------------------------
// MID tier (round-9 verified path): int2 sorted, random ew gather in pull.
// ---------------------------------------------------------------------------
__global__ __launch_bounds__(256) void k_reorder_sh(const int4* __restrict__ src4,
                                                    const int4* __restrict__ dst4,
                                                    const int* __restrict__ src,
                                                    const int* __restrict__ dst,
                                                    int* __restrict__ cursor,
                                                    int2* __restrict__ sorted,
                                                    int E, int rng)
{
    int shard = blockIdx.x & (NXCD - 1);
    int wg    = blockIdx.x / NXCD;
    int lo    = shard * rng;
    int hi    = lo + rng;
    int E4    = E >> 2;

    int base = wg * 512;
    int stop = min(base + 512, E4);
    for (int i = base + threadIdx.x; i < stop; i += 256) {
        int4 d = dst4[i];
        bool any = (d.x >= lo && d.x < hi) | (d.y >= lo && d.y < hi) |
                   (d.z >= lo && d.z < hi) | (d.w >= lo && d.w < hi);
        if (!any) continue;
        int4 s = src4[i];
        int e = i * 4;
        if (d.x >= lo && d.x < hi) sorted[atomicAdd(cursor + d.x, 1)] = make_int2(s.x, e + 0);
        if (d.y >= lo && d.y < hi) sorted[atomicAdd(cursor + d.y, 1)] = make_int2(s.y, e + 1);
        if (d.z >= lo && d.z < hi) sorted[atomicAdd(cursor + d.z, 1)] = make_int2(s.z, e + 2);
        if (d.w >= lo && d.w < hi) sorted[atomicAdd(cursor + d.w, 1)] = make_int2(s.w, e + 3);
    }
    if (wg == 0 && threadIdx.x < (E & 3)) {
        int e = (E & ~3) + threadIdx.x;
        int d = dst[e];
        if (d >= lo && d < hi) sorted[atomicAdd(cursor + d, 1)] = make_int2(src[e], e);
    }
}

__global__ __launch_bounds__(256) void k_pull(const float4* __restrict__ feat4,
                                              const float4* __restrict__ ew4,
                                              const int2* __restrict__ sorted,
                                              const int* __restrict__ offsets,
                                              float4* __restrict__ acc_h4,
                                              float4* __restrict__ acc_w4, int N)
{
    int t = blockIdx.x * 256 + threadIdx.x;
    int node = t >> 4;
    if (node >= N) return;
    int l = t & 15;

    int beg = offsets[node];
    int end = offsets[node + 1];

    float4 ah = feat4[(size_t)node * 16 + l];
    float4 aw = make_float4(0.f, 0.f, 0.f, 0.f);

    if (beg < end) {
        int2 r0 = sorted[beg];
        int2 r1 = (beg + 1 < end) ? sorted[beg + 1] : make_int2(0, 0);
        for (int p = beg; p < end; ++p) {
            int2 rn = (p + 2 < end) ? sorted[p + 2] : make_int2(0, 0);
            f4add(ah, feat4[(size_t)r0.x * 16 + l]);
            if (l < 4) f4add(aw, ew4[(size_t)r0.y * 4 + l]);
            r0 = r1; r1 = rn;
        }
    }

    acc_h4[(size_t)node * 16 + l] = ah;
    if (l < 4) acc_w4[(size_t)node * 4 + l] = aw;
}

// ---------------------------------------------------------------------------
// Last-resort fallback: atomic scatter.
// ---------------------------------------------------------------------------
__global__ __launch_bounds__(256) void scatter_kernel(
    const float4* __restrict__ feat4, const float4* __restrict__ ew4,
    const int* __restrict__ src, const int* __restrict__ dst,
    float* __restrict__ acc_h, float* __restrict__ acc_w, int E)
{
    int t = blockIdx.x * 256 + threadIdx.x;
    int e = t >> 4;
    if (e >= E) return;
    int l = t & 15;
    int s = src[e];
    int d = dst[e];
    float4 hv = feat4[(size_t)s * 16 + l];
    float4 wv;
    bool do_w = (l < 4);
    if (do_w) wv = ew4[(size_t)e * 4 + l];
    float* p = acc_h + (size_t)d * D_IN + l * 4;
    unsafeAtomicAdd(p + 0, hv.x);
    unsafeAtomicAdd(p + 1, hv.y);
    unsafeAtomicAdd(p + 2, hv.z);
    unsafeAtomicAdd(p + 3, hv.w);
    if (do_w) {
        float* q = acc_w + (size_t)d * E_W + l * 4;
        unsafeAtomicAdd(q + 0, wv.x);
        unsafeAtomicAdd(q + 1, wv.y);
        unsafeAtomicAdd(q + 2, wv.z);
        unsafeAtomicAdd(q + 3, wv.w);
    }
}

// ---------------------------------------------------------------------------
// out = relu(x @ W + b); k-loop unroll capped at 4 (r4: spill at full unroll).
// ---------------------------------------------------------------------------
__global__ __launch_bounds__(256) void gemm_relu_kernel(
    const float* __restrict__ feat, const float* __restrict__ acc_w,
    const float* __restrict__ Wm, const float* __restrict__ bias,
    float* __restrict__ out, int N, int add_feat)
{
    __shared__ float4 Wl[D_MSG * 16];
    __shared__ float4 bl4[16];
    __shared__ float  xs[64 * 84];

    for (int i = threadIdx.x; i < D_MSG * 16; i += 256)
        Wl[i] = ((const float4*)Wm)[i];
    if (threadIdx.x < 16)
        bl4[threadIdx.x] = ((const float4*)bias)[threadIdx.x];

    const int tc   = threadIdx.x & 15;
    const int tg   = threadIdx.x >> 4;
    const int base = blockIdx.x * 64;

    for (int i = threadIdx.x; i < 64 * 20; i += 256) {
        int r = i / 20, c = i % 20;
        int row = base + r;
        float4 v = make_float4(0.f, 0.f, 0.f, 0.f);
        if (row < N) {
            if (c < 16) {
                v = ((const float4*)out)[(size_t)row * 16 + c];
                if (add_feat) {
                    float4 f = ((const float4*)feat)[(size_t)row * 16 + c];
                    f4add(v, f);
                }
            } else {
                v = ((const float4*)acc_w)[(size_t)row * 4 + (c - 16)];
            }
        }
        *((float4*)&xs[r * 84 + c * 4]) = v;
    }
    __syncthreads();

    float4 ob = bl4[tc];
    float4 acc[4];
    acc[0] = ob; acc[1] = ob; acc[2] = ob; acc[3] = ob;

    #pragma unroll 4
    for (int k = 0; k < D_MSG; ++k) {
        float4 w = Wl[k * 16 + tc];
        #pragma unroll
        for (int rr = 0; rr < 4; ++rr) {
            float xk = xs[(tg * 4 + rr) * 84 + k];
            acc[rr].x += xk * w.x;
            acc[rr].y += xk * w.y;
            acc[rr].z += xk * w.z;
            acc[rr].w += xk * w.w;
        }
    }

    #pragma unroll
    for (int rr = 0; rr < 4; ++rr) {
        int row = base + tg * 4 + rr;
        if (row < N) {
            float4 v = acc[rr];
            v.x = fmaxf(v.x, 0.f);
            v.y = fmaxf(v.y, 0.f);
            v.z = fmaxf(v.z, 0.f);
            v.w = fmaxf(v.w, 0.f);
            ((float4*)out)[(size_t)row * 16 + tc] = v;
        }
    }
}

static inline size_t align256(size_t x) { return (x + 255) & ~(size_t)255; }

extern "C" void kernel_launch(void* const* d_in, const int* in_sizes, int n_in,
                              void* d_out, int out_size, void* d_ws, size_t ws_size,
                              hipStream_t stream) {
    const float* feat   = (const float*)d_in[0];
    const float* edge_w = (const float*)d_in[1];
    const float* Wm     = (const float*)d_in[2];
    const float* bias   = (const float*)d_in[3];
    const int*   src    = (const int*)d_in[4];
    const int*   dst    = (const int*)d_in[5];
    float* out = (float*)d_out;

    const int N = in_sizes[0] / D_IN;
    const int E = in_sizes[4];

    // ---- shared workspace prefix ----
    size_t o_accw   = 0;
    size_t o_deg    = align256(o_accw + (size_t)N * E_W * 4);
    size_t o_excl   = align256(o_deg  + (size_t)(N + 1) * 4);
    size_t o_off    = align256(o_excl + (size_t)N * 4);
    size_t o_cur    = align256(o_off  + (size_t)(N + 1) * 4);
    size_t o_bsum   = align256(o_cur  + (size_t)N * 4);
    size_t o_bexcl  = align256(o_bsum + 256 * 4);
    size_t o_tail   = align256(o_bexcl + 256 * 4);
    // FULL tier: ssrc[E] + sew[E*16 floats]
    size_t o_ssrc   = o_tail;
    size_t o_sew    = align256(o_ssrc + (size_t)E * 4);
    size_t need_full = o_sew + (size_t)E * 64;
    // MID tier: sorted int2[E]
    size_t o_sorted = o_tail;
    size_t need_mid = o_sorted + (size_t)E * 8;

    char* ws = (char*)d_ws;
    float* acc_w = (float*)(ws + o_accw);

    int used_fallback = 0;

    if (ws_size >= need_mid) {
        int* deg     = (int*)(ws + o_deg);
        int* excl    = (int*)(ws + o_excl);
        int* offsets = (int*)(ws + o_off);
        int* cursor  = (int*)(ws + o_cur);
        int* bsums   = (int*)(ws + o_bsum);
        int* bexcl   = (int*)(ws + o_bexcl);

        hipMemsetAsync(deg, 0, (size_t)(N + 1) * 4, stream);

        const int rng = (N + NXCD - 1) / NXCD;
        const int E4  = E >> 2;
        const int wg_per_shard = (E4 + 511) / 512;
        const int grid_sh = wg_per_shard * NXCD;

        k_hist_sh<<<grid_sh, 256, 0, stream>>>((const int4*)dst, dst, deg, E, rng);

        int nb1 = (N + 1023) / 1024;       // assumes nb1 <= 256 (N <= 262144)
        k_scan1<<<nb1, 256, 0, stream>>>(deg, excl, bsums, N);
        k_scan2<<<1, 256, 0, stream>>>(bsums, bexcl, nb1);
        k_scan3<<<(N + 255) / 256, 256, 0, stream>>>(excl, bexcl, offsets, cursor, N, E);

        if (ws_size >= need_full) {
            int*    ssrc = (int*)   (ws + o_ssrc);
            float4* sew4 = (float4*)(ws + o_sew);
            k_reorder_ew<<<grid_sh, 256, 0, stream>>>(
                (const int4*)src, (const int4*)dst, src, dst,
                (const float4*)edge_w, cursor, ssrc, sew4, E, rng);
            k_pull_seq<<<(N * 16 + 255) / 256, 256, 0, stream>>>(
                (const float4*)feat, sew4, ssrc, offsets,
                (float4*)out, (float4*)acc_w, N);
        } else {
            int2* sorted = (int2*)(ws + o_sorted);
            k_reorder_sh<<<grid_sh, 256, 0, stream>>>(
                (const int4*)src, (const int4*)dst, src, dst, cursor, sorted, E, rng);
            k_pull<<<(N * 16 + 255) / 256, 256, 0, stream>>>(
                (const float4*)feat, (const float4*)edge_w, sorted, offsets,
                (float4*)out, (float4*)acc_w, N);
        }
    } else {
        used_fallback = 1;
        hipMemsetAsync(d_out, 0, (size_t)N * D_IN * sizeof(float), stream);
        hipMemsetAsync(acc_w, 0, (size_t)N * E_W * sizeof(float), stream);
        long long tot = (long long)E * 16;
        scatter_kernel<<<(int)((tot + 255) / 256), 256, 0, stream>>>(
            (const float4*)feat, (const float4*)edge_w, src, dst, out, acc_w, E);
    }

    gemm_relu_kernel<<<(N + 63) / 64, 256, 0, stream>>>(
        feat, acc_w, Wm, bias, out, N, used_fallback);
}

// Round 12
// 417.434 us; speedup vs baseline: 1.2425x; 1.2425x over previous
//
#include <hip/hip_runtime.h>

#define D_IN  64
#define E_W   16
#define D_MSG 80
#define NXCD  8

static __device__ __forceinline__ void f4add(float4& a, const float4& b) {
    a.x += b.x; a.y += b.y; a.z += b.z; a.w += b.w;
}

// ---------------------------------------------------------------------------
// CSR build step 1: degree histogram, XCD-sharded (round-9, kept).
// ---------------------------------------------------------------------------
__global__ __launch_bounds__(256) void k_hist_sh(const int4* __restrict__ dst4,
                                                 const int* __restrict__ dst,
                                                 int* __restrict__ deg,
                                                 int E, int rng)
{
    int shard = blockIdx.x & (NXCD - 1);
    int wg    = blockIdx.x / NXCD;
    int lo    = shard * rng;
    int hi    = lo + rng;
    int E4    = E >> 2;

    int base = wg * 512;
    int stop = min(base + 512, E4);
    for (int i = base + threadIdx.x; i < stop; i += 256) {
        int4 d = dst4[i];
        if (d.x >= lo && d.x < hi) atomicAdd(deg + d.x, 1);
        if (d.y >= lo && d.y < hi) atomicAdd(deg + d.y, 1);
        if (d.z >= lo && d.z < hi) atomicAdd(deg + d.z, 1);
        if (d.w >= lo && d.w < hi) atomicAdd(deg + d.w, 1);
    }
    if (wg == 0 && threadIdx.x < (E & 3)) {
        int e = (E & ~3) + threadIdx.x;
        int d = dst[e];
        if (d >= lo && d < hi) atomicAdd(deg + d, 1);
    }
}

// ---------------------------------------------------------------------------
// CSR build step 2: 3-phase exclusive scan.
// ---------------------------------------------------------------------------
__global__ __launch_bounds__(256) void k_scan1(const int* __restrict__ deg,
                                               int* __restrict__ excl,
                                               int* __restrict__ bsums, int n)
{
    __shared__ int ts[256];
    int base = blockIdx.x * 1024 + threadIdx.x * 4;
    int v[4], s = 0;
    #pragma unroll
    for (int i = 0; i < 4; ++i) { v[i] = (base + i < n) ? deg[base + i] : 0; s += v[i]; }
    ts[threadIdx.x] = s; __syncthreads();
    #pragma unroll
    for (int off = 1; off < 256; off <<= 1) {
        int t = (threadIdx.x >= off) ? ts[threadIdx.x - off] : 0;
        __syncthreads();
        ts[threadIdx.x] += t;
        __syncthreads();
    }
    int run = ts[threadIdx.x] - s;
    if (threadIdx.x == 255) bsums[blockIdx.x] = ts[255];
    #pragma unroll
    for (int i = 0; i < 4; ++i) {
        if (base + i < n) excl[base + i] = run;
        run += v[i];
    }
}

__global__ __launch_bounds__(256) void k_scan2(int* __restrict__ bsums,
                                               int* __restrict__ bexcl, int nb)
{
    __shared__ int ts[256];
    int v = (threadIdx.x < nb) ? bsums[threadIdx.x] : 0;
    ts[threadIdx.x] = v; __syncthreads();
    #pragma unroll
    for (int off = 1; off < 256; off <<= 1) {
        int t = (threadIdx.x >= off) ? ts[threadIdx.x - off] : 0;
        __syncthreads();
        ts[threadIdx.x] += t;
        __syncthreads();
    }
    bexcl[threadIdx.x] = ts[threadIdx.x] - v;
}

__global__ __launch_bounds__(256) void k_scan3(const int* __restrict__ excl,
                                               const int* __restrict__ bexcl,
                                               int* __restrict__ offsets,
                                               int* __restrict__ cursor, int n, int E)
{
    int i = blockIdx.x * 256 + threadIdx.x;
    if (i < n) {
        int s = excl[i] + bexcl[i >> 10];
        offsets[i] = s;
        cursor[i]  = s;
    }
    if (i == 0) offsets[n] = E;
}

// ---------------------------------------------------------------------------
// CSR build step 3: scatter (src,eid) into dst-sorted order, XCD-sharded
// (round-9 verified path; the round-11 edge_w payload fold REGRESSED:
//  scattered 64B stores -> 2x write amplification, 212MB HBM writes).
// ---------------------------------------------------------------------------
__global__ __launch_bounds__(256) void k_reorder_sh(const int4* __restrict__ src4,
                                                    const int4* __restrict__ dst4,
                                                    const int* __restrict__ src,
                                                    const int* __restrict__ dst,
                                                    int* __restrict__ cursor,
                                                    int2* __restrict__ sorted,
                                                    int E, int rng)
{
    int shard = blockIdx.x & (NXCD - 1);
    int wg    = blockIdx.x / NXCD;
    int lo    = shard * rng;
    int hi    = lo + rng;
    int E4    = E >> 2;

    int base = wg * 512;
    int stop = min(base + 512, E4);
    for (int i = base + threadIdx.x; i < stop; i += 256) {
        int4 d = dst4[i];
        bool any = (d.x >= lo && d.x < hi) | (d.y >= lo && d.y < hi) |
                   (d.z >= lo && d.z < hi) | (d.w >= lo && d.w < hi);
        if (!any) continue;
        int4 s = src4[i];
        int e = i * 4;
        if (d.x >= lo && d.x < hi) sorted[atomicAdd(cursor + d.x, 1)] = make_int2(s.x, e + 0);
        if (d.y >= lo && d.y < hi) sorted[atomicAdd(cursor + d.y, 1)] = make_int2(s.y, e + 1);
        if (d.z >= lo && d.z < hi) sorted[atomicAdd(cursor + d.z, 1)] = make_int2(s.z, e + 2);
        if (d.w >= lo && d.w < hi) sorted[atomicAdd(cursor + d.w, 1)] = make_int2(s.w, e + 3);
    }
    if (wg == 0 && threadIdx.x < (E & 3)) {
        int e = (E & ~3) + threadIdx.x;
        int d = dst[e];
        if (d >= lo && d < hi) sorted[atomicAdd(cursor + d, 1)] = make_int2(src[e], e);
    }
}

// ---------------------------------------------------------------------------
// Pull aggregation, UNROLL-4 for memory-level parallelism.
// Round-9 profile: 106us, HBM 40%, VALUBusy 17%, occ 73% -> latency-bound,
// ~1-2 loads in flight per thread. Batch 4 independent records' loads before
// accumulating -> 4x in-flight gathers. VGPR was 20; +16 is free.
// ---------------------------------------------------------------------------
__global__ __launch_bounds__(256) void k_pull(const float4* __restrict__ feat4,
                                              const float4* __restrict__ ew4,
                                              const int2* __restrict__ sorted,
                                              const int* __restrict__ offsets,
                                              float4* __restrict__ acc_h4,
                                              float4* __restrict__ acc_w4, int N)
{
    int t = blockIdx.x * 256 + threadIdx.x;
    int node = t >> 4;
    if (node >= N) return;
    int l = t & 15;

    int beg = offsets[node];
    int end = offsets[node + 1];

    float4 ah = feat4[(size_t)node * 16 + l];   // eps-residual (EPS=0)
    float4 aw = make_float4(0.f, 0.f, 0.f, 0.f);

    int p = beg;
    for (; p + 4 <= end; p += 4) {
        int2 r0 = sorted[p + 0];
        int2 r1 = sorted[p + 1];
        int2 r2 = sorted[p + 2];
        int2 r3 = sorted[p + 3];
        float4 f0 = feat4[(size_t)r0.x * 16 + l];
        float4 f1 = feat4[(size_t)r1.x * 16 + l];
        float4 f2 = feat4[(size_t)r2.x * 16 + l];
        float4 f3 = feat4[(size_t)r3.x * 16 + l];
        if (l < 4) {
            float4 w0 = ew4[(size_t)r0.y * 4 + l];
            float4 w1 = ew4[(size_t)r1.y * 4 + l];
            float4 w2 = ew4[(size_t)r2.y * 4 + l];
            float4 w3 = ew4[(size_t)r3.y * 4 + l];
            f4add(aw, w0); f4add(aw, w1); f4add(aw, w2); f4add(aw, w3);
        }
        f4add(ah, f0); f4add(ah, f1); f4add(ah, f2); f4add(ah, f3);
    }
    for (; p < end; ++p) {
        int2 r = sorted[p];
        f4add(ah, feat4[(size_t)r.x * 16 + l]);
        if (l < 4) f4add(aw, ew4[(size_t)r.y * 4 + l]);
    }

    acc_h4[(size_t)node * 16 + l] = ah;
    if (l < 4) acc_w4[(size_t)node * 4 + l] = aw;
}

// ---------------------------------------------------------------------------
// Last-resort fallback: atomic scatter.
// ---------------------------------------------------------------------------
__global__ __launch_bounds__(256) void scatter_kernel(
    const float4* __restrict__ feat4, const float4* __restrict__ ew4,
    const int* __restrict__ src, const int* __restrict__ dst,
    float* __restrict__ acc_h, float* __restrict__ acc_w, int E)
{
    int t = blockIdx.x * 256 + threadIdx.x;
    int e = t >> 4;
    if (e >= E) return;
    int l = t & 15;
    int s = src[e];
    int d = dst[e];
    float4 hv = feat4[(size_t)s * 16 + l];
    float4 wv;
    bool do_w = (l < 4);
    if (do_w) wv = ew4[(size_t)e * 4 + l];
    float* p = acc_h + (size_t)d * D_IN + l * 4;
    unsafeAtomicAdd(p + 0, hv.x);
    unsafeAtomicAdd(p + 1, hv.y);
    unsafeAtomicAdd(p + 2, hv.z);
    unsafeAtomicAdd(p + 3, hv.w);
    if (do_w) {
        float* q = acc_w + (size_t)d * E_W + l * 4;
        unsafeAtomicAdd(q + 0, wv.x);
        unsafeAtomicAdd(q + 1, wv.y);
        unsafeAtomicAdd(q + 2, wv.z);
        unsafeAtomicAdd(q + 3, wv.w);
    }
}

// ---------------------------------------------------------------------------
// out = relu(x @ W + b); k-loop unroll capped at 4 (r4: spill at full unroll).
// ---------------------------------------------------------------------------
__global__ __launch_bounds__(256) void gemm_relu_kernel(
    const float* __restrict__ feat, const float* __restrict__ acc_w,
    const float* __restrict__ Wm, const float* __restrict__ bias,
    float* __restrict__ out, int N, int add_feat)
{
    __shared__ float4 Wl[D_MSG * 16];
    __shared__ float4 bl4[16];
    __shared__ float  xs[64 * 84];

    for (int i = threadIdx.x; i < D_MSG * 16; i += 256)
        Wl[i] = ((const float4*)Wm)[i];
    if (threadIdx.x < 16)
        bl4[threadIdx.x] = ((const float4*)bias)[threadIdx.x];

    const int tc   = threadIdx.x & 15;
    const int tg   = threadIdx.x >> 4;
    const int base = blockIdx.x * 64;

    for (int i = threadIdx.x; i < 64 * 20; i += 256) {
        int r = i / 20, c = i % 20;
        int row = base + r;
        float4 v = make_float4(0.f, 0.f, 0.f, 0.f);
        if (row < N) {
            if (c < 16) {
                v = ((const float4*)out)[(size_t)row * 16 + c];
                if (add_feat) {
                    float4 f = ((const float4*)feat)[(size_t)row * 16 + c];
                    f4add(v, f);
                }
            } else {
                v = ((const float4*)acc_w)[(size_t)row * 4 + (c - 16)];
            }
        }
        *((float4*)&xs[r * 84 + c * 4]) = v;
    }
    __syncthreads();

    float4 ob = bl4[tc];
    float4 acc[4];
    acc[0] = ob; acc[1] = ob; acc[2] = ob; acc[3] = ob;

    #pragma unroll 4
    for (int k = 0; k < D_MSG; ++k) {
        float4 w = Wl[k * 16 + tc];
        #pragma unroll
        for (int rr = 0; rr < 4; ++rr) {
            float xk = xs[(tg * 4 + rr) * 84 + k];
            acc[rr].x += xk * w.x;
            acc[rr].y += xk * w.y;
            acc[rr].z += xk * w.z;
            acc[rr].w += xk * w.w;
        }
    }

    #pragma unroll
    for (int rr = 0; rr < 4; ++rr) {
        int row = base + tg * 4 + rr;
        if (row < N) {
            float4 v = acc[rr];
            v.x = fmaxf(v.x, 0.f);
            v.y = fmaxf(v.y, 0.f);
            v.z = fmaxf(v.z, 0.f);
            v.w = fmaxf(v.w, 0.f);
            ((float4*)out)[(size_t)row * 16 + tc] = v;
        }
    }
}

static inline size_t align256(size_t x) { return (x + 255) & ~(size_t)255; }

extern "C" void kernel_launch(void* const* d_in, const int* in_sizes, int n_in,
                              void* d_out, int out_size, void* d_ws, size_t ws_size,
                              hipStream_t stream) {
    const float* feat   = (const float*)d_in[0];
    const float* edge_w = (const float*)d_in[1];
    const float* Wm     = (const float*)d_in[2];
    const float* bias   = (const float*)d_in[3];
    const int*   src    = (const int*)d_in[4];
    const int*   dst    = (const int*)d_in[5];
    float* out = (float*)d_out;

    const int N = in_sizes[0] / D_IN;
    const int E = in_sizes[4];

    // ---- workspace layout (round-9) ----
    size_t o_accw   = 0;
    size_t o_deg    = align256(o_accw + (size_t)N * E_W * 4);
    size_t o_excl   = align256(o_deg  + (size_t)(N + 1) * 4);
    size_t o_off    = align256(o_excl + (size_t)N * 4);
    size_t o_cur    = align256(o_off  + (size_t)(N + 1) * 4);
    size_t o_bsum   = align256(o_cur  + (size_t)N * 4);
    size_t o_bexcl  = align256(o_bsum + 256 * 4);
    size_t o_sorted = align256(o_bexcl + 256 * 4);
    size_t need     = o_sorted + (size_t)E * 8;

    char* ws = (char*)d_ws;
    float* acc_w = (float*)(ws + o_accw);

    int used_fallback = 0;

    if (ws_size >= need) {
        int*  deg     = (int*) (ws + o_deg);
        int*  excl    = (int*) (ws + o_excl);
        int*  offsets = (int*) (ws + o_off);
        int*  cursor  = (int*) (ws + o_cur);
        int*  bsums   = (int*) (ws + o_bsum);
        int*  bexcl   = (int*) (ws + o_bexcl);
        int2* sorted  = (int2*)(ws + o_sorted);

        hipMemsetAsync(deg, 0, (size_t)(N + 1) * 4, stream);

        const int rng = (N + NXCD - 1) / NXCD;
        const int E4  = E >> 2;
        const int wg_per_shard = (E4 + 511) / 512;
        const int grid_sh = wg_per_shard * NXCD;

        k_hist_sh<<<grid_sh, 256, 0, stream>>>((const int4*)dst, dst, deg, E, rng);

        int nb1 = (N + 1023) / 1024;       // assumes nb1 <= 256 (N <= 262144)
        k_scan1<<<nb1, 256, 0, stream>>>(deg, excl, bsums, N);
        k_scan2<<<1, 256, 0, stream>>>(bsums, bexcl, nb1);
        k_scan3<<<(N + 255) / 256, 256, 0, stream>>>(excl, bexcl, offsets, cursor, N, E);

        k_reorder_sh<<<grid_sh, 256, 0, stream>>>(
            (const int4*)src, (const int4*)dst, src, dst, cursor, sorted, E, rng);

        k_pull<<<(N * 16 + 255) / 256, 256, 0, stream>>>(
            (const float4*)feat, (const float4*)edge_w, sorted, offsets,
            (float4*)out, (float4*)acc_w, N);
    } else {
        used_fallback = 1;
        hipMemsetAsync(d_out, 0, (size_t)N * D_IN * sizeof(float), stream);
        hipMemsetAsync(acc_w, 0, (size_t)N * E_W * sizeof(float), stream);
        long long tot = (long long)E * 16;
        scatter_kernel<<<(int)((tot + 255) / 256), 256, 0, stream>>>(
            (const float4*)feat, (const float4*)edge_w, src, dst, out, acc_w, E);
    }

    gemm_relu_kernel<<<(N + 63) / 64, 256, 0, stream>>>(
        feat, acc_w, Wm, bias, out, N, used_fallback);
}